// Round 5
// baseline (174.486 us; speedup 1.0000x reference)
//
#include <hip/hip_runtime.h>
#include <hip/hip_bf16.h>

// DeformableConv1D: B=4, Cin=256, Cout=256, L=8192, K=7, stride=1, pad=3, dil=1
// out[b,o,l] = sum_{i,kt} w[o,i,kt] * interp(b, l, i, kt) + bias[o]
//
// Round 15 = Round 14 (63.2us) + two LDS/VMEM-pipe fixes:
//  - (a) Il column swizzle: 16B-unit u -> u ^ ((row>>3)&3). r14 counters
//    showed exactly +4 cyc bank-conflict per ds_read_b128 (3.67M / 918k
//    reads), from rows m and m+8 aliasing (row stride 116 dwords ≡ 20 mod
//    32, period 8). The XOR only touches the quad bits, so it folds into
//    per-lane constants qxA/qxB (ro 0/32 vs 16/48) -> zero per-read VALU.
//    Writes get the same XOR via snl3 (q is compile-time, 1 v_xor/CVT).
//  - (b) gather via ONE aligned 4-dword load per channel instead of two
//    dependent dwords: p0 = min(xc & ~1, LEN-4) is 8B-aligned and in
//    bounds; parity/clamp folds into 4 static coefs d0..d3 (2 nonzero;
//    extra terms are +0*x, value-preserving). Halves gather instructions
//    and vmcnt queue depth.
// Schedule, (512,2), cvt_pk pack: unchanged from r14.

#define B_    4
#define CIN   256
#define COUT  256
#define LEN   8192
#define KK    7
#define NTOT  (B_ * LEN)          // 32768 = 1<<15
#define QTOT  (CIN * KK)          // 1792
#define LPITCH 232                // LDS row pitch (elems); 464 B

typedef short s16x8 __attribute__((ext_vector_type(8)));
typedef int   s32x4 __attribute__((ext_vector_type(4)));
typedef float f32x4 __attribute__((ext_vector_type(4)));
typedef f32x4 f32x4a8 __attribute__((aligned(8)));   // 8B-aligned vector load

static __device__ __forceinline__ unsigned f2bf(float f) {
  union { float f; unsigned u; } u; u.f = f;
  unsigned r = u.u + 0x7FFF + ((u.u >> 16) & 1);   // RNE (finite inputs)
  return r >> 16;
}

// packed pair: lo16 = bf16(a), hi16 = bf16(b); RNE, same bits as f2bf|f2bf<<16
static __device__ __forceinline__ int cvt_pk_bf16(float a, float b) {
  int r;
  asm("v_cvt_pk_bf16_f32 %0, %1, %2" : "=v"(r) : "v"(a), "v"(b));
  return r;
}

// ---------------------------------------------------------------------------
// Kernel 1: offset-conv partials. (unchanged)
// ---------------------------------------------------------------------------
__global__ __launch_bounds__(256) void loc_partial(
    const float* __restrict__ X, const float* __restrict__ OW,
    float* __restrict__ Partial) {
  __shared__ float red[4][256][KK];            // 28672 B

  const int t    = threadIdx.x;
  const int lane = t & 63;
  const int wu   = __builtin_amdgcn_readfirstlane(t >> 6);
  const int cg   = blockIdx.x >> 7;            // 0..3
  const int nb   = (blockIdx.x & 127) << 8;    // 256 n per block
  const int b    = nb >> 13;
  const int l0   = nb & (LEN - 1);

  float acc[KK][4];
#pragma unroll
  for (int k = 0; k < KK; ++k)
#pragma unroll
    for (int r = 0; r < 4; ++r) acc[k][r] = 0.0f;

#pragma unroll 2
  for (int ii = 0; ii < 16; ++ii) {
    const int i = cg * 64 + wu * 16 + ii;      // uniform
    float owv[49];
#pragma unroll
    for (int k = 0; k < KK; ++k)
#pragma unroll
      for (int j = 0; j < KK; ++j)
        owv[k * 7 + j] = OW[(k * CIN + i) * KK + j];   // uniform -> s_load

    const float* xr = X + ((size_t)(b * CIN + i) << 13);
#pragma unroll
    for (int r = 0; r < 4; ++r) {
      const int lr = l0 + lane + 64 * r;
      float xv[KK];
#pragma unroll
      for (int j = 0; j < KK; ++j) {
        int pos = lr + j - 3;
        xv[j] = ((unsigned)pos < LEN) ? xr[pos] : 0.0f;
      }
#pragma unroll
      for (int k = 0; k < KK; ++k)
#pragma unroll
        for (int j = 0; j < KK; ++j)
          acc[k][r] += xv[j] * owv[k * 7 + j];
    }
  }

#pragma unroll
  for (int k = 0; k < KK; ++k)
#pragma unroll
    for (int r = 0; r < 4; ++r) red[wu][lane + 64 * r][k] = acc[k][r];
  __syncthreads();

#pragma unroll
  for (int k = 0; k < KK; ++k) {
    float s = red[0][t][k] + red[1][t][k] + red[2][t][k] + red[3][t][k];
    Partial[((size_t)(cg * 7 + k) << 15) + nb + t] = s;   // coalesced
  }
}

// ---------------------------------------------------------------------------
// Kernel 2: Loc[k][n] = (l+k) + OB[k] + sum_cg Partial[cg*7+k][n] (unchanged)
// ---------------------------------------------------------------------------
__global__ __launch_bounds__(256) void loc_reduce(
    const float* __restrict__ Partial, const float* __restrict__ OB,
    float* __restrict__ Loc) {
  int n = blockIdx.x * 256 + threadIdx.x;      // grid 128 -> 32768
  int l = n & (LEN - 1);
#pragma unroll
  for (int k = 0; k < KK; ++k) {
    float s = (float)(l + k) + OB[k];
#pragma unroll
    for (int cg = 0; cg < 4; ++cg)
      s += Partial[((size_t)(cg * 7 + k) << 15) + n];
    Loc[((size_t)k << 15) + n] = s;
  }
}

// ---------------------------------------------------------------------------
// Kernel 3: weights -> bf16 A-fragments via LDS. (unchanged)
// ---------------------------------------------------------------------------
__global__ __launch_bounds__(256) void wt_build(
    const float* __restrict__ W, unsigned short* __restrict__ Wf) {
  __shared__ float Wl[16 * 32 * KK];           // 14336 B
  const int t  = threadIdx.x;
  const int ot = blockIdx.x >> 3;
  const int c  = blockIdx.x & 7;

  for (int e = t; e < 16 * 32 * KK; e += 256) {
    int o = e / 224;
    int r = e - o * 224;
    Wl[e] = W[(size_t)(ot * 16 + o) * QTOT + c * 224 + r];
  }
  __syncthreads();

  const int lane = t & 63;
  const int sg   = t >> 6;
  const int ol   = lane & 15;
  const int ig   = lane >> 4;
  for (int s = sg; s < KK; s += 4) {
    s16x8 v;
#pragma unroll
    for (int j = 0; j < 8; ++j)
      v[j] = (short)f2bf(Wl[ol * 224 + (ig * 8 + j) * KK + s]);
    int f = (ot * 8 + c) * KK + s;
    *(s16x8*)(Wf + ((size_t)f << 9) + (lane << 3)) = v;
  }
}

// ---------------------------------------------------------------------------
// Kernel 4: main MFMA GEMM (r10 fused schedule + swizzled Il + x4 gather).
// Block = 512 threads (8 waves), 256 o x 64 n, grid 512 (= 2 blocks/CU).
// ---------------------------------------------------------------------------
__global__ __launch_bounds__(512, 2) void main_kernel(
    const float* __restrict__ X, const unsigned short* __restrict__ Wf,
    const float* __restrict__ Bias, const float* __restrict__ Loc,
    float* __restrict__ Out) {
  __shared__ unsigned short Il[2][64][LPITCH];   // 59392 B

  const int t    = threadIdx.x;
  const int lane = t & 63;
  const int w    = t >> 6;                     // 0..7
  const int n0   = blockIdx.x << 6;            // grid 512
  const int b    = n0 >> 13;
  const float* Xb = X + ((size_t)b << 21);

  const bool stager = (t < 448);
  const int nl = t & 63;
  const int kt = t >> 6;                       // 0..6 when stager

  // stager: aligned gather base + 4 static interp coefficients
  int p0 = 0;
  float d0 = 0.f, d1 = 0.f, d2 = 0.f, d3 = 0.f;
  if (stager) {
    float locv = Loc[((size_t)kt << 15) + n0 + nl];
    int x0  = (int)floorf(locv);
    int x0c = min(max(x0, 0), LEN - 1);
    int x1c = min(max(x0 + 1, 0), LEN - 1);
    float wa = (float)x1c - locv;
    float wb = locv - (float)x0c;
    bool hi = (x0 >= LEN - 1);
    bool lo = (x0 < 0);
    float c0 = (hi ? 0.f : wa) + (lo ? wb : 0.f);   // coeff of x[xc]
    float c1 = (hi ? wa : 0.f) + (lo ? 0.f : wb);   // coeff of x[xc+1]
    int xc = min(max(x0, 0), LEN - 2);
    p0 = min(xc & ~1, LEN - 4);                // 8B-aligned, p0+3 <= LEN-1
    int off = xc - p0;                         // 0, 1, or 2
    d0 = (off == 0) ? c0 : 0.f;
    d1 = (off == 1) ? c0 : ((off == 0) ? c1 : 0.f);
    d2 = (off == 2) ? c0 : ((off == 1) ? c1 : 0.f);
    d3 = (off == 2) ? c1 : 0.f;
  }

  f32x4 acc[2][4];
#pragma unroll
  for (int a = 0; a < 2; ++a)
#pragma unroll
    for (int cc = 0; cc < 4; ++cc) acc[a][cc] = (f32x4){0.f, 0.f, 0.f, 0.f};

  const int mrow = lane & 15;
  const int quad = lane >> 4;

  // swizzle constants (elems): column unit u -> u ^ ((row>>3)&3)
  const int mr3  = mrow >> 3;
  const int snl3 = ((nl >> 3) & 3) << 3;                 // stager write XOR
  const int qxA  = (quad << 3) ^ ((mr3 & 3) << 3);       // read rows ro=0,32
  const int qxB  = (quad << 3) ^ (((2 + mr3) & 3) << 3); // read rows ro=16,48

  f32x4 fv[8];                                 // gather quarter (32 VGPR)

#define GATHER_Q(chunk, q)                                        \
  if (stager) {                                                   \
    _Pragma("unroll")                                             \
    for (int m = 0; m < 8; ++m)                                   \
      fv[m] = *(const f32x4a8*)(Xb + p0 +                         \
               (((chunk) * 32 + (q) * 8 + m) << 13));             \
  }

#define CVT_Q(dst, q)                                             \
  if (stager) {                                                   \
    s32x4 vv;                                                     \
    _Pragma("unroll")                                             \
    for (int m = 0; m < 4; ++m) {                                 \
      f32x4 u = fv[2 * m], v = fv[2 * m + 1];                     \
      float a = d0 * u[0] + d1 * u[1] + d2 * u[2] + d3 * u[3];    \
      float e = d0 * v[0] + d1 * v[1] + d2 * v[2] + d3 * v[3];    \
      vv[m] = cvt_pk_bf16(a, e);                                  \
    }                                                             \
    *(s32x4*)((dst) + nl * LPITCH + kt * 32 + (((q) << 3) ^ snl3)) = vv; \
  }

#define AFL(ttv, sv)                                              \
  (*(const s16x8*)(Wf + ((size_t)(((w * 2 + (ttv)) * 8 + c) * KK + (sv)) << 9) + (lane << 3)))

#define MSTEP(sv, a0, a1) {                                                        \
    const s16x8 b0 = *(const s16x8*)(Icur + (mrow)      * LPITCH + (sv) * 32 + qxA); \
    const s16x8 b1 = *(const s16x8*)(Icur + (16 + mrow) * LPITCH + (sv) * 32 + qxB); \
    acc[0][0] = __builtin_amdgcn_mfma_f32_16x16x32_bf16(a0, b0, acc[0][0], 0, 0, 0); \
    acc[1][0] = __builtin_amdgcn_mfma_f32_16x16x32_bf16(a1, b0, acc[1][0], 0, 0, 0); \
    acc[0][1] = __builtin_amdgcn_mfma_f32_16x16x32_bf16(a0, b1, acc[0][1], 0, 0, 0); \
    acc[1][1] = __builtin_amdgcn_mfma_f32_16x16x32_bf16(a1, b1, acc[1][1], 0, 0, 0); \
    const s16x8 b2 = *(const s16x8*)(Icur + (32 + mrow) * LPITCH + (sv) * 32 + qxA); \
    const s16x8 b3 = *(const s16x8*)(Icur + (48 + mrow) * LPITCH + (sv) * 32 + qxB); \
    acc[0][2] = __builtin_amdgcn_mfma_f32_16x16x32_bf16(a0, b2, acc[0][2], 0, 0, 0); \
    acc[1][2] = __builtin_amdgcn_mfma_f32_16x16x32_bf16(a1, b2, acc[1][2], 0, 0, 0); \
    acc[0][3] = __builtin_amdgcn_mfma_f32_16x16x32_bf16(a0, b3, acc[0][3], 0, 0, 0); \
    acc[1][3] = __builtin_amdgcn_mfma_f32_16x16x32_bf16(a1, b3, acc[1][3], 0, 0, 0); \
  }

  // prologue: stage chunk 0 into Il[0]
  {
    unsigned short* I0 = &Il[0][0][0];
    GATHER_Q(0, 0) CVT_Q(I0, 0)
    GATHER_Q(0, 1) CVT_Q(I0, 1)
    GATHER_Q(0, 2) CVT_Q(I0, 2)
    GATHER_Q(0, 3) CVT_Q(I0, 3)
  }
  __syncthreads();

  for (int c = 0; c < 8; ++c) {
    const int cur = c & 1;
    const unsigned short* Icur = &Il[cur][0][0];
    unsigned short*       Inxt = &Il[cur ^ 1][0][0];

    // af fragments for s=0..3 FIRST (before any gather this chunk)
    s16x8 afA[2][4];
#pragma unroll
    for (int tt = 0; tt < 2; ++tt)
#pragma unroll
      for (int s = 0; s < 4; ++s) afA[tt][s] = AFL(tt, s);
    __builtin_amdgcn_sched_barrier(0);

    if (c < 7) { GATHER_Q(c + 1, 0) }
    MSTEP(0, afA[0][0], afA[1][0])
    if (c < 7) { CVT_Q(Inxt, 0) GATHER_Q(c + 1, 1) }
    MSTEP(1, afA[0][1], afA[1][1])

    // af fragments for s=4..6 (before gather quarters 2,3)
    s16x8 afB[2][3];
#pragma unroll
    for (int tt = 0; tt < 2; ++tt)
#pragma unroll
      for (int s = 0; s < 3; ++s) afB[tt][s] = AFL(tt, 4 + s);
    __builtin_amdgcn_sched_barrier(0);

    if (c < 7) { CVT_Q(Inxt, 1) GATHER_Q(c + 1, 2) }
    MSTEP(2, afA[0][2], afA[1][2])
    if (c < 7) { CVT_Q(Inxt, 2) GATHER_Q(c + 1, 3) }
    MSTEP(3, afA[0][3], afA[1][3])
    if (c < 7) { CVT_Q(Inxt, 3) }
    MSTEP(4, afB[0][0], afB[1][0])
    MSTEP(5, afB[0][1], afB[1][1])
    MSTEP(6, afB[0][2], afB[1][2])
    if (c < 7) __syncthreads();
  }
#undef GATHER_Q
#undef CVT_Q
#undef AFL
#undef MSTEP

  // epilogue: D row m = quad*4+r (o), col = mrow (l)
  const int lbase = (n0 & (LEN - 1)) + mrow;
#pragma unroll
  for (int tt = 0; tt < 2; ++tt) {
    const int obase = (w * 2 + tt) * 16 + quad * 4;
#pragma unroll
    for (int r = 0; r < 4; ++r) {
      const int o = obase + r;
      const float bv = Bias[o];
      float* orow = Out + (((size_t)(b * COUT + o)) << 13) + lbase;
#pragma unroll
      for (int nt = 0; nt < 4; ++nt)
        orow[nt * 16] = acc[tt][nt][r] + bv;
    }
  }
}

extern "C" void kernel_launch(void* const* d_in, const int* in_sizes, int n_in,
                              void* d_out, int out_size, void* d_ws, size_t ws_size,
                              hipStream_t stream) {
  const float* X    = (const float*)d_in[0];   // (4,256,8192)
  const float* W    = (const float*)d_in[1];   // (256,256,7)
  const float* Bias = (const float*)d_in[2];   // (256,)
  const float* OW   = (const float*)d_in[3];   // (7,256,7)
  const float* OB   = (const float*)d_in[4];   // (7,)
  float* Out = (float*)d_out;                  // (4,256,8192)

  // ws: Loc (0.92 MB) | Wf (0.92 MB) | Partial (3.5 MB)  = 5.4 MB
  float* Loc = (float*)d_ws;
  unsigned short* Wf = (unsigned short*)(Loc + (size_t)NTOT * KK);
  float* Partial = (float*)(Wf + (size_t)COUT * QTOT);

  loc_partial<<<4 * 128, 256, 0, stream>>>(X, OW, Partial);
  loc_reduce<<<NTOT / 256, 256, 0, stream>>>(Partial, OB, Loc);
  wt_build<<<128, 256, 0, stream>>>(W, Wf);
  main_kernel<<<NTOT / 64, 512, 0, stream>>>(X, Wf, Bias, Loc, Out);
}